// Round 8
// baseline (206.690 us; speedup 1.0000x reference)
//
#include <hip/hip_runtime.h>
#include <hip/hip_bf16.h>
#include <stdint.h>

// Problem: B=2, N=4096, C=512, H=4, D=128.  MemoryEfficientAttention forward.
// cast3(f32->bf16) -> QKV GEMM (MFMA bf16, K pre-scaled, V transposed via LDS
// bounce, XCD A-slab block order) -> flash attention (BQ=64/BKV=64, 8 waves,
// q x kv split, 72KB LDS -> 2 blocks/CU, swizzled Ps) -> proj GEMM (f32 out).
constexpr int B_  = 2;
constexpr int N_  = 4096;
constexpr int C_  = 512;
constexpr int H_  = 4;
constexpr int D_  = 128;
constexpr int M_  = B_ * N_;     // 8192
constexpr int TC_ = 3 * C_;      // 1536
constexpr float SCALE_  = 0.08838834764831845f;   // 1/sqrt(128)
constexpr float LOG2E_  = 1.4426950408889634f;
constexpr float KSCALE_ = SCALE_ * LOG2E_;        // folded into K at production

typedef __attribute__((ext_vector_type(8))) short short8;   // 8 bf16 = 4 VGPR
typedef __attribute__((ext_vector_type(4))) float f32x4;    // MFMA C/D

#define GLOBAL_AS __attribute__((address_space(1)))
#define LDS_AS    __attribute__((address_space(3)))

// Direct global->LDS DMA, 16B/lane. LDS dest must be wave-uniform base + lane*16.
static __device__ __forceinline__ void load_lds16(const void* gp, void* lp) {
    __builtin_amdgcn_global_load_lds((const GLOBAL_AS void*)gp, (LDS_AS void*)lp,
                                     16, 0, 0);
}

static __device__ __forceinline__ uint16_t f2bf(float f) {
    uint32_t u = __builtin_bit_cast(uint32_t, f);
    uint32_t r = (u + 0x7FFFu + ((u >> 16) & 1u)) >> 16;   // RNE
    return (uint16_t)r;
}
static __device__ __forceinline__ uint32_t cvt_pk_bf16(float lo, float hi) {
    uint32_t r;
    asm("v_cvt_pk_bf16_f32 %0, %1, %2" : "=v"(r) : "v"(lo), "v"(hi));
    return r;   // low16 = bf16(lo), high16 = bf16(hi)
}
// exp2 via single v_exp_f32 (register-only asm: no scheduling hazard).
static __device__ __forceinline__ float exp2f_fast(float x) {
    float r;
    asm("v_exp_f32 %0, %1" : "=v"(r) : "v"(x));
    return r;
}

// ---------------------------------------------------------------------------
// Fused cast f32 -> bf16 for x, qkv_w, proj_w.  One block = 2048 elems.
// Grid 2560 = 2048 (x) + 384 (w) + 128 (pw), exact coverage.
// ---------------------------------------------------------------------------
__global__ __launch_bounds__(256)
void cast3_kernel(const float* __restrict__ x,  const float* __restrict__ w,
                  const float* __restrict__ pw,
                  uint16_t* __restrict__ xb, uint16_t* __restrict__ wb,
                  uint16_t* __restrict__ pwb)
{
    const int bid = blockIdx.x;
    const float* src; uint16_t* dst; int i;
    if (bid < 2048)      { src = x;  dst = xb;  i = bid * 256 + threadIdx.x; }
    else if (bid < 2432) { src = w;  dst = wb;  i = (bid - 2048) * 256 + threadIdx.x; }
    else                 { src = pw; dst = pwb; i = (bid - 2432) * 256 + threadIdx.x; }
    float4 a = reinterpret_cast<const float4*>(src)[2*i];
    float4 b = reinterpret_cast<const float4*>(src)[2*i+1];
    uint4 o;
    o.x = (uint32_t)f2bf(a.x) | ((uint32_t)f2bf(a.y) << 16);
    o.y = (uint32_t)f2bf(a.z) | ((uint32_t)f2bf(a.w) << 16);
    o.z = (uint32_t)f2bf(b.x) | ((uint32_t)f2bf(b.y) << 16);
    o.w = (uint32_t)f2bf(b.z) | ((uint32_t)f2bf(b.w) << 16);
    reinterpret_cast<uint4*>(dst)[i] = o;
}

// ---------------------------------------------------------------------------
// QKV GEMM (NT): Y[m][o] = sum_k xb[m][k]*wb[o][k] + bias[o].
// 128x128 tile, BK=64, 4 waves, mfma 16x16x32 bf16, global_load_lds staging.
// 1-D grid, mt = bid&63, nt = bid>>6  =>  bid%8 = mt%8: each XCD owns a 1 MB
// A-slab (8 m-tiles) x all n-tiles; slab + full B (1.5 MB) fit 4 MB L2.
// Epilogue: Q -> [B,H,N,D]; K -> same * KSCALE_; V -> [B,H,D,N] via LDS-bounce.
// ---------------------------------------------------------------------------
__global__ __launch_bounds__(256, 2)
void gemm_qkv(const uint16_t* __restrict__ A,   // xb [8192][512]
              const uint16_t* __restrict__ Bw,  // wb [1536][512]
              const float* __restrict__ bias,   // [1536]
              uint16_t* __restrict__ Qb,
              uint16_t* __restrict__ Kb,
              uint16_t* __restrict__ Vt)
{
    __shared__ __align__(16) uint16_t SMEM[128 * 128];   // As | Bs, reused as T
    uint16_t* As = SMEM;                // [128][64]
    uint16_t* Bs = SMEM + 128 * 64;     // [128][64]

    const int tid  = threadIdx.x;
    const int lane = tid & 63;
    const int w    = tid >> 6;
    const int wr   = w >> 1, wc = w & 1;
    const int cq   = lane & 15;
    const int g    = lane >> 4;
    const int bid  = blockIdx.x;
    const int m0   = (bid & 63) << 7;   // XCD slab: bid%8 = m-tile%8
    const int o0   = (bid >> 6) << 7;

    f32x4 acc[4][4];
    const f32x4 zf = {0.f, 0.f, 0.f, 0.f};
    #pragma unroll
    for (int i = 0; i < 4; ++i)
        #pragma unroll
        for (int j = 0; j < 4; ++j) acc[i][j] = zf;

    for (int kt = 0; kt < C_; kt += 64) {
        __syncthreads();
        #pragma unroll
        for (int i = 0; i < 4; ++i) {            // 1024 16B slots per tile
            int s = tid + 256 * i;
            int row = s >> 3, p = s & 7, c = p ^ (row & 7);
            load_lds16(A  + (size_t)(m0 + row) * C_ + kt + c * 8, &As[row*64 + p*8]);
            load_lds16(Bw + (size_t)(o0 + row) * C_ + kt + c * 8, &Bs[row*64 + p*8]);
        }
        __syncthreads();                         // compiler drains vmcnt here
        #pragma unroll
        for (int ks = 0; ks < 2; ++ks) {
            short8 af[4], bfr[4];
            #pragma unroll
            for (int mi = 0; mi < 4; ++mi) {
                int r = 64*wr + 16*mi + cq;
                af[mi] = *reinterpret_cast<const short8*>(
                    &As[r*64 + (((g + 4*ks) ^ (r & 7)) * 8)]);
            }
            #pragma unroll
            for (int ni = 0; ni < 4; ++ni) {
                int r = 64*wc + 16*ni + cq;
                bfr[ni] = *reinterpret_cast<const short8*>(
                    &Bs[r*64 + (((g + 4*ks) ^ (r & 7)) * 8)]);
            }
            #pragma unroll
            for (int mi = 0; mi < 4; ++mi)
                #pragma unroll
                for (int ni = 0; ni < 4; ++ni)
                    acc[mi][ni] = __builtin_amdgcn_mfma_f32_16x16x32_bf16(
                        af[mi], bfr[ni], acc[mi][ni], 0, 0, 0);
        }
    }

    // Epilogue. o-tile is 128-aligned -> sec and h are block-uniform.
    const int sec = o0 >> 9;
    const int h   = (o0 >> 7) & 3;
    if (sec < 2) {
        // Q / K: direct stores, [B,H,N,D]
        #pragma unroll
        for (int ni = 0; ni < 4; ++ni) {
            const int o = o0 + 64*wc + 16*ni + cq;
            const int d = o & 127;
            const float bv = bias[o];
            #pragma unroll
            for (int mi = 0; mi < 4; ++mi) {
                #pragma unroll
                for (int r = 0; r < 4; ++r) {
                    const int m = m0 + 64*wr + 16*mi + 4*g + r;
                    const int b = m >> 12;
                    const int n = m & (N_ - 1);
                    const float y = acc[mi][ni][r] + bv;
                    if (sec == 0)
                        Qb[(((size_t)b*H_ + h)*N_ + n)*D_ + d] = f2bf(y);
                    else
                        Kb[(((size_t)b*H_ + h)*N_ + n)*D_ + d] = f2bf(y * KSCALE_);
                }
            }
        }
    } else {
        // V: bounce acc through LDS (T[o_local=128][m_local=128]) -> coalesced
        // transposed stores to Vt [B,H,D,N].
        __syncthreads();                 // all compute reads of As/Bs done
        uint16_t* T = SMEM;              // [128][128]
        #pragma unroll
        for (int ni = 0; ni < 4; ++ni) {
            const int ol = 64*wc + 16*ni + cq;
            const float bv = bias[o0 + ol];
            #pragma unroll
            for (int mi = 0; mi < 4; ++mi) {
                const int ml = 64*wr + 16*mi + 4*g;
                const uint32_t w0 = (uint32_t)f2bf(acc[mi][ni][0] + bv)
                                  | ((uint32_t)f2bf(acc[mi][ni][1] + bv) << 16);
                const uint32_t w1 = (uint32_t)f2bf(acc[mi][ni][2] + bv)
                                  | ((uint32_t)f2bf(acc[mi][ni][3] + bv) << 16);
                *reinterpret_cast<uint2*>(&T[ol*128 + ml]) = make_uint2(w0, w1);
            }
        }
        __syncthreads();
        const int b = m0 >> 12;          // m-range never crosses batch boundary
        #pragma unroll
        for (int i = 0; i < 8; ++i) {    // 128 o-rows x 16 m-chunks
            int s = tid + 256 * i;
            int ro = s >> 4, mc = s & 15;
            int4 v = *reinterpret_cast<const int4*>(&T[ro*128 + mc*8]);
            const int n = (m0 & (N_ - 1)) + mc*8;
            *reinterpret_cast<int4*>(
                &Vt[(((size_t)b*H_ + h)*D_ + ro)*N_ + n]) = v;
        }
    }
}

// ---------------------------------------------------------------------------
// Flash attention v3.  512 threads = 8 waves.  BQ=64, BKV=64.
// Wave w: q-block (w&3, 16 q rows, 1 frag col-set), kv-half (w>>2, 32 kv).
// Per-wave online softmax (exp2 domain, K pre-scaled, defer-max); O^T =
// V^T·P^T, cols = q = lane&15 -> in-lane rescale; 2-way LDS merge at end.
// LDS: Ks 2x16K + Vs 2x16K + Ps 8K = 72 KB -> 2 blocks/CU = 4 waves/SIMD,
// with per-block independent barriers (phase-offset overlap).
// Ps pair-preserving XOR swizzle (c8 ^= (cq&3)<<1): writes <=2-way, reads at
// the 8-lane/bank-quad floor.  Grid 512: bh = bid&7 -> XCD-affine head.
// ---------------------------------------------------------------------------
__global__ __launch_bounds__(512, 4)
void attn_kernel(const uint16_t* __restrict__ Qb,
                 const uint16_t* __restrict__ Kb,   // pre-scaled by KSCALE_
                 const uint16_t* __restrict__ Vt,   // [B,H,D,N]
                 uint16_t* __restrict__ ctx)        // [B,N,C] bf16, c = h*128+d
{
    __shared__ __align__(16) uint16_t Ks[2][64 * 128];   // 2 x 16 KB
    __shared__ __align__(16) uint16_t Vs[2][128 * 64];   // 2 x 16 KB ([d][kv])
    __shared__ __align__(16) uint16_t Ps[8 * 512];       // per-wave [16 q][32 kv]

    const int tid  = threadIdx.x;
    const int lane = tid & 63;
    const int w    = tid >> 6;      // 0..7
    const int qb   = w & 3;         // q-block (16 rows)
    const int kvh  = w >> 2;        // kv half (32 rows of 64)
    const int cq   = lane & 15;
    const int g    = lane >> 4;

    const int bid = blockIdx.x;
    const int bh  = bid & 7;        // XCD-affine head
    const int qt  = bid >> 3;       // q-tile 0..63 (64 q each)
    const int b   = bh >> 2, h = bh & 3;

    const uint16_t* Qg = Qb + ((size_t)bh * N_ + qt * 64 + qb * 16) * D_;
    const uint16_t* Kg = Kb + (size_t)bh * N_ * D_;
    const uint16_t* Vg = Vt + (size_t)bh * D_ * N_;

    auto stage = [&](int tn, int bb) {
        const int kv0 = tn * 64;
        #pragma unroll
        for (int i = 0; i < 2; ++i) {            // K tile [kv=64][d=128]
            int s = tid + 512 * i;
            int row = s >> 4, p = s & 15, c = p ^ (row & 15);
            load_lds16(Kg + (size_t)(kv0 + row) * D_ + c * 8,
                       &Ks[bb][row * 128 + p * 8]);
        }
        #pragma unroll
        for (int i = 0; i < 2; ++i) {            // V^T tile [d=128][kv=64]
            int s = tid + 512 * i;
            int row = s >> 3, p = s & 7, c = p ^ (row & 7);
            load_lds16(Vg + (size_t)row * N_ + kv0 + c * 8,
                       &Vs[bb][row * 64 + p * 8]);
        }
    };

    stage(0, 0);

    // Q fragments (one 16-row block per wave), global -> regs, kernel-lifetime.
    short8 qreg[4];
    {
        const uint16_t* qrow = Qg + (size_t)cq * D_;
        #pragma unroll
        for (int ks = 0; ks < 4; ++ks)
            qreg[ks] = *reinterpret_cast<const short8*>(qrow + 32*ks + 8*g);
    }

    float m_run = -3.0e38f, l_run = 0.f;
    f32x4 o_acc[8];                  // O^T partial: rows d (16df+4g+r), col q=cq
    const f32x4 zf = {0.f, 0.f, 0.f, 0.f};
    #pragma unroll
    for (int df = 0; df < 8; ++df) o_acc[df] = zf;

    __syncthreads();                 // stage(0) landed for all waves

    for (int t = 0; t < N_ / 64; ++t) {
        const int cur = t & 1;
        if (t + 1 < N_ / 64) stage(t + 1, cur ^ 1);   // issue early, land late

        // ---- S^T(half) = K(half)·Q^T : 2 kv-frags x 4 d-ksteps ----
        f32x4 sacc[2];
        sacc[0] = zf; sacc[1] = zf;
        #pragma unroll
        for (int ks = 0; ks < 4; ++ks) {
            #pragma unroll
            for (int kvf = 0; kvf < 2; ++kvf) {
                const int row = kvh*32 + 16*kvf + cq;
                const short8 ak = *reinterpret_cast<const short8*>(
                    &Ks[cur][row * 128 + (((g + 4*ks) ^ cq) * 8)]);
                sacc[kvf] = __builtin_amdgcn_mfma_f32_16x16x32_bf16(
                    ak, qreg[ks], sacc[kvf], 0, 0, 0);
            }
        }

        // ---- per-wave softmax (exp2 domain, defer-max) ----
        float pmax = -3.0e38f;
        #pragma unroll
        for (int kvf = 0; kvf < 2; ++kvf)
            #pragma unroll
            for (int r = 0; r < 4; ++r)
                pmax = fmaxf(pmax, sacc[kvf][r]);
        pmax = fmaxf(pmax, __shfl_xor(pmax, 16));
        pmax = fmaxf(pmax, __shfl_xor(pmax, 32));

        if (__any(pmax > m_run + 8.f)) {
            const float mnew = fmaxf(m_run, pmax);
            const float corr = exp2f_fast(m_run - mnew);
            m_run = mnew;
            l_run *= corr;
            #pragma unroll
            for (int df = 0; df < 8; ++df)
                #pragma unroll
                for (int r = 0; r < 4; ++r)
                    o_acc[df][r] *= corr;        // in-lane: col = my q
        }

        float lsum = 0.f;
        #pragma unroll
        for (int kvf = 0; kvf < 2; ++kvf) {
            const float p0 = exp2f_fast(sacc[kvf][0] - m_run);
            const float p1 = exp2f_fast(sacc[kvf][1] - m_run);
            const float p2 = exp2f_fast(sacc[kvf][2] - m_run);
            const float p3 = exp2f_fast(sacc[kvf][3] - m_run);
            lsum += (p0 + p1) + (p2 + p3);
            // logical 8B-chunk c8 = 4kvf+g; phys = c8 ^ ((cq&3)<<1)
            const int c8p = (4*kvf + g) ^ ((cq & 3) << 1);
            *reinterpret_cast<uint2*>(&Ps[w*512 + cq*32 + c8p*4]) =
                make_uint2(cvt_pk_bf16(p0, p1), cvt_pk_bf16(p2, p3));
        }
        lsum += __shfl_xor(lsum, 16);
        lsum += __shfl_xor(lsum, 32);
        l_run += lsum;

        // P^T B-frag: logical 16B chunk g, phys g ^ (cq&3)
        const short8 bp = *reinterpret_cast<const short8*>(
            &Ps[w*512 + cq*32 + ((g ^ (cq & 3)) << 3)]);

        // ---- O^T(partial) += V^T(:,half) · P^T  (one K=32 step) ----
        #pragma unroll
        for (int df = 0; df < 8; ++df) {
            const int row = 16*df + cq;
            const int ch  = (4*kvh + g) ^ (cq & 7);
            const short8 av = *reinterpret_cast<const short8*>(
                &Vs[cur][row * 64 + ch * 8]);
            o_acc[df] = __builtin_amdgcn_mfma_f32_16x16x32_bf16(
                av, bp, o_acc[df], 0, 0, 0);
        }
        __syncthreads();   // next tile staged + everyone done with buf cur
    }

    // ---- merge kv-halves (waves qb / qb+4) via LDS, then write ctx ----
    float* mbuf = reinterpret_cast<float*>(&Vs[0][0]);        // 64 floats
    float* lbuf = mbuf + 64;                                  // 64 floats
    f32x4* obuf = reinterpret_cast<f32x4*>(&Ks[0][0]);        // 2048 f32x4 = 32K

    if (kvh == 1) {
        mbuf[qb*16 + cq] = m_run;    // 4 g-dups, same value
        lbuf[qb*16 + cq] = l_run;
        #pragma unroll
        for (int df = 0; df < 8; ++df)
            obuf[(qb*8 + df)*64 + lane] = o_acc[df];
    }
    __syncthreads();
    if (kvh == 0) {
        const float mB = mbuf[qb*16 + cq];
        const float lB = lbuf[qb*16 + cq];
        const float ms = fmaxf(m_run, mB);
        const float cA = exp2f_fast(m_run - ms);
        const float cB = exp2f_fast(mB - ms);
        const float inv = 1.f / (l_run * cA + lB * cB);

        const int n = qt*64 + qb*16 + cq;
        uint16_t* dst = ctx + ((size_t)b * N_ + n) * C_ + h * D_;
        #pragma unroll
        for (int df = 0; df < 8; ++df) {
            const f32x4 oB = obuf[(qb*8 + df)*64 + lane];
            float v0 = (o_acc[df][0]*cA + oB[0]*cB) * inv;
            float v1 = (o_acc[df][1]*cA + oB[1]*cB) * inv;
            float v2 = (o_acc[df][2]*cA + oB[2]*cB) * inv;
            float v3 = (o_acc[df][3]*cA + oB[3]*cB) * inv;
            const uint32_t w0 = (uint32_t)f2bf(v0) | ((uint32_t)f2bf(v1) << 16);
            const uint32_t w1 = (uint32_t)f2bf(v2) | ((uint32_t)f2bf(v3) << 16);
            *reinterpret_cast<uint2*>(&dst[16*df + 4*g]) = make_uint2(w0, w1);
        }
    }
}

// ---------------------------------------------------------------------------
// Proj GEMM: out = ctx @ proj_w^T + bias, f32 out.  Same XCD A-slab remap.
// ---------------------------------------------------------------------------
__global__ __launch_bounds__(256, 2)
void gemm_proj(const uint16_t* __restrict__ A,   // ctx [8192][512]
               const uint16_t* __restrict__ Bw,  // pwb [512][512]
               const float* __restrict__ bias,   // [512]
               float* __restrict__ out)          // [8192][512] f32
{
    __shared__ __align__(16) uint16_t As[128 * 64];
    __shared__ __align__(16) uint16_t Bs[128 * 64];

    const int tid  = threadIdx.x;
    const int lane = tid & 63;
    const int w    = tid >> 6;
    const int wr   = w >> 1, wc = w & 1;
    const int cq   = lane & 15;
    const int g    = lane >> 4;
    const int bid  = blockIdx.x;
    const int m0   = (bid & 63) << 7;   // XCD slab: bid%8 = m-tile%8
    const int o0   = (bid >> 6) << 7;

    f32x4 acc[4][4];
    const f32x4 zf = {0.f, 0.f, 0.f, 0.f};
    #pragma unroll
    for (int i = 0; i < 4; ++i)
        #pragma unroll
        for (int j = 0; j < 4; ++j) acc[i][j] = zf;

    for (int kt = 0; kt < C_; kt += 64) {
        __syncthreads();
        #pragma unroll
        for (int i = 0; i < 4; ++i) {
            int s = tid + 256 * i;
            int row = s >> 3, p = s & 7, c = p ^ (row & 7);
            load_lds16(A  + (size_t)(m0 + row) * C_ + kt + c * 8, &As[row*64 + p*8]);
            load_lds16(Bw + (size_t)(o0 + row) * C_ + kt + c * 8, &Bs[row*64 + p*8]);
        }
        __syncthreads();
        #pragma unroll
        for (int ks = 0; ks < 2; ++ks) {
            short8 af[4], bfr[4];
            #pragma unroll
            for (int mi = 0; mi < 4; ++mi) {
                int r = 64*wr + 16*mi + cq;
                af[mi] = *reinterpret_cast<const short8*>(
                    &As[r*64 + (((g + 4*ks) ^ (r & 7)) * 8)]);
            }
            #pragma unroll
            for (int ni = 0; ni < 4; ++ni) {
                int r = 64*wc + 16*ni + cq;
                bfr[ni] = *reinterpret_cast<const short8*>(
                    &Bs[r*64 + (((g + 4*ks) ^ (r & 7)) * 8)]);
            }
            #pragma unroll
            for (int mi = 0; mi < 4; ++mi)
                #pragma unroll
                for (int ni = 0; ni < 4; ++ni)
                    acc[mi][ni] = __builtin_amdgcn_mfma_f32_16x16x32_bf16(
                        af[mi], bfr[ni], acc[mi][ni], 0, 0, 0);
        }
    }

    #pragma unroll
    for (int ni = 0; ni < 4; ++ni) {
        const int o = o0 + 64*wc + 16*ni + cq;
        const float bv = bias[o];
        #pragma unroll
        for (int mi = 0; mi < 4; ++mi) {
            #pragma unroll
            for (int r = 0; r < 4; ++r) {
                const int m = m0 + 64*wr + 16*mi + 4*g + r;
                out[(size_t)m * C_ + o] = acc[mi][ni][r] + bv;
            }
        }
    }
}

// ---------------------------------------------------------------------------
extern "C" void kernel_launch(void* const* d_in, const int* in_sizes, int n_in,
                              void* d_out, int out_size, void* d_ws, size_t ws_size,
                              hipStream_t stream)
{
    const float* x      = (const float*)d_in[0];
    const float* qkv_w  = (const float*)d_in[1];
    const float* qkv_b  = (const float*)d_in[2];
    const float* proj_w = (const float*)d_in[3];
    const float* proj_b = (const float*)d_in[4];
    float* out = (float*)d_out;

    // ws layout (bf16 elems): xb | wb | pwb | Qb | Kb | Vt | ctx
    uint16_t* xb  = (uint16_t*)d_ws;
    uint16_t* wb  = xb  + (size_t)M_ * C_;           // 4194304
    uint16_t* pwb = wb  + (size_t)TC_ * C_;          //  786432
    uint16_t* Qb  = pwb + (size_t)C_ * C_;           //  262144
    uint16_t* Kb  = Qb  + (size_t)B_ * H_ * N_ * D_; // 4194304 each
    uint16_t* Vt  = Kb  + (size_t)B_ * H_ * N_ * D_;
    uint16_t* ctx = Vt  + (size_t)B_ * H_ * N_ * D_;

    cast3_kernel<<<2560, 256, 0, stream>>>(x, qkv_w, proj_w, xb, wb, pwb);
    gemm_qkv<<<(M_/128) * (TC_/128), 256, 0, stream>>>(xb, wb, qkv_b, Qb, Kb, Vt);
    attn_kernel<<<(N_/64) * (B_*H_), 512, 0, stream>>>(Qb, Kb, Vt, ctx);
    gemm_proj<<<(M_/128) * (C_/128), 256, 0, stream>>>(ctx, pwb, proj_b, out);
}